// Round 6
// baseline (316.847 us; speedup 1.0000x reference)
//
#include <hip/hip_runtime.h>
#include <math.h>

constexpr int DIM = 64;
constexpr int S = 8;
constexpr int WPB = 16;                // waves per block (1024 threads)
constexpr int BLOCK = WPB * 64;
constexpr int GRID = 512;              // 2 blocks/CU -> 32 waves/CU; grid-stride over batch
constexpr int WSTR = 68;               // W^T LDS row stride (~0 conflicts measured in R2)

// DPP quad-perm lane exchange (VALU pipe, not DS) — correctness verified R3/R4
template <int CTRL>
__device__ __forceinline__ float dppx(float x) {
    return __builtin_bit_cast(float,
        __builtin_amdgcn_mov_dpp(__builtin_bit_cast(int, x), CTRL, 0xf, 0xf, true));
}
#define XOR1 0xB1   // quad_perm(1,0,3,2)
#define XOR2 0x4E   // quad_perm(2,3,0,1)

// 8-way softmax over lanes' (lane&7) scores; broadcasts w[0..7] to all lanes.
__device__ __forceinline__ void octet_softmax(float sc, float* wout) {
    float m = sc;
    m = fmaxf(m, dppx<XOR1>(m));
    m = fmaxf(m, dppx<XOR2>(m));
    m = fmaxf(m, __shfl_xor(m, 4));
    float e = __expf(sc - m);
    float s = e;
    s += dppx<XOR1>(s);
    s += dppx<XOR2>(s);
    s += __shfl_xor(s, 4);
    float w = e / s;
    #pragma unroll
    for (int k = 0; k < 8; k++) wout[k] = __shfl(w, k);   // lane k (mod 8) holds s=k
}

__global__ __launch_bounds__(BLOCK, 8)
void sestkgcn_kernel(
    const int*   __restrict__ u_idx,
    const int*   __restrict__ v_idx,
    const float* __restrict__ usr_feat,
    const float* __restrict__ item_feat,
    const float* __restrict__ rel_feat,
    const int*   __restrict__ neigh_uu,
    const float* __restrict__ neigh_uu_st,
    const int*   __restrict__ neigh_ui,
    const float* __restrict__ neigh_ui_rat,
    const float* __restrict__ neigh_ui_vot,
    const float* __restrict__ neigh_ui_tim,
    const int*   __restrict__ neigh_iu,
    const float* __restrict__ neigh_iu_rat,
    const float* __restrict__ neigh_iu_vot,
    const float* __restrict__ neigh_iu_tim,
    const int*   __restrict__ neigh_ii,
    const int*   __restrict__ neigh_ir,
    const float* __restrict__ Wu,
    const float* __restrict__ bu,
    const float* __restrict__ Wv,
    const float* __restrict__ bv,
    float*       __restrict__ out,
    int n)
{
    __shared__ float sWuT[DIM * WSTR];
    __shared__ float sWvT[DIM * WSTR];
    __shared__ float sbu[DIM];
    __shared__ float sbv[DIM];
    __shared__ float xs[WPB * DIM];

    const int tid = threadIdx.x;
    for (int i = tid; i < DIM * DIM; i += BLOCK) {
        const int d_ = i >> 6, j_ = i & 63;
        sWuT[j_ * WSTR + d_] = Wu[i];
        sWvT[j_ * WSTR + d_] = Wv[i];
    }
    if (tid < DIM) { sbu[tid] = bu[tid]; sbv[tid] = bv[tid]; }
    __syncthreads();

    const int wave = tid >> 6;
    const int lane = tid & 63;
    const int ls   = lane & 7;

    float* xw = &xs[wave * DIM];
    const float4* wuT = (const float4*)&sWuT[lane * WSTR];
    const float4* wvT = (const float4*)&sWvT[lane * WSTR];
    const float4* xw4 = (const float4*)xw;
    const float bu_l = sbu[lane];
    const float bv_l = sbv[lane];

    const int stride = GRID * WPB;
    int b = blockIdx.x * WPB + wave;
    if (b >= n) return;

    int u = u_idx[b];
    int v = v_idx[b];

    while (b < n) {
        // prefetch next iteration's indices (breaks one level of the dep chain)
        const int b2 = b + stride;
        const int bc = (b2 < n) ? b2 : b;
        const int u_nxt = u_idx[bc];
        const int v_nxt = v_idx[bc];

        const unsigned u8 = (unsigned)u << 3, v8 = (unsigned)v << 3;

        // ---- issue ALL first-level loads up front (max loads in flight) ----
        const float u_d = usr_feat[((unsigned)u << 6) | (unsigned)lane];
        const float v_d = item_feat[((unsigned)v << 6) | (unsigned)lane];

        const float sc_uu_raw = neigh_uu_st[u8 + ls];
        const float r_ui = neigh_ui_rat[u8 + ls], vo_ui = neigh_ui_vot[u8 + ls], t_ui = neigh_ui_tim[u8 + ls];
        const float r_iu = neigh_iu_rat[v8 + ls], vo_iu = neigh_iu_vot[v8 + ls], t_iu = neigh_iu_tim[v8 + ls];

        const int4 uu0 = ((const int4*)(neigh_uu + u8))[0];
        const int4 uu1 = ((const int4*)(neigh_uu + u8))[1];
        const int4 ui0 = ((const int4*)(neigh_ui + u8))[0];
        const int4 ui1 = ((const int4*)(neigh_ui + u8))[1];
        const int4 iu0 = ((const int4*)(neigh_iu + v8))[0];
        const int4 iu1 = ((const int4*)(neigh_iu + v8))[1];
        const int4 ii0 = ((const int4*)(neigh_ii + v8))[0];
        const int4 ii1 = ((const int4*)(neigh_ii + v8))[1];
        const int4 ir0 = ((const int4*)(neigh_ir + v8))[0];
        const int4 ir1 = ((const int4*)(neigh_ir + v8))[1];

        const float sc_ui = r_ui * vo_ui * t_ui;
        const float sc_iu = r_iu * vo_iu * t_iu;

        // ---------------- user side ----------------
        float w[S];
        octet_softmax(sc_uu_raw, w);
        float agg_uu = 0.f;
        {
            const int ni[S] = {uu0.x, uu0.y, uu0.z, uu0.w, uu1.x, uu1.y, uu1.z, uu1.w};
            float r[S];
            #pragma unroll
            for (int s = 0; s < S; s++) r[s] = usr_feat[((unsigned)ni[s] << 6) | (unsigned)lane];
            #pragma unroll
            for (int s = 0; s < S; s++) agg_uu = fmaf(w[s], r[s], agg_uu);
        }

        octet_softmax(sc_ui, w);
        float agg_ui = 0.f;
        {
            const int ni[S] = {ui0.x, ui0.y, ui0.z, ui0.w, ui1.x, ui1.y, ui1.z, ui1.w};
            float r[S];
            #pragma unroll
            for (int s = 0; s < S; s++) r[s] = item_feat[((unsigned)ni[s] << 6) | (unsigned)lane];
            #pragma unroll
            for (int s = 0; s < S; s++) agg_ui = fmaf(w[s], r[s], agg_ui);
        }

        // user_h = relu(x @ Wu + bu)
        float hu;
        {
            xw[lane] = u_d + agg_uu + agg_ui;
            __threadfence_block();
            float a0 = 0.f, a1 = 0.f, a2 = 0.f, a3 = 0.f;
            #pragma unroll
            for (int k = 0; k < DIM / 4; k++) {
                float4 xv = xw4[k];
                float4 wv = wuT[k];
                a0 = fmaf(xv.x, wv.x, a0);
                a1 = fmaf(xv.y, wv.y, a1);
                a2 = fmaf(xv.z, wv.z, a2);
                a3 = fmaf(xv.w, wv.w, a3);
            }
            hu = fmaxf((a0 + a1) + (a2 + a3) + bu_l, 0.f);
        }

        // ---------------- item side ----------------
        octet_softmax(sc_iu, w);
        float agg_iu = 0.f;
        {
            const int ni[S] = {iu0.x, iu0.y, iu0.z, iu0.w, iu1.x, iu1.y, iu1.z, iu1.w};
            float r[S];
            #pragma unroll
            for (int s = 0; s < S; s++) r[s] = usr_feat[((unsigned)ni[s] << 6) | (unsigned)lane];
            #pragma unroll
            for (int s = 0; s < S; s++) agg_iu = fmaf(w[s], r[s], agg_iu);
        }

        // KG attention: merge 8 dot-products so lane holds total for s=lane&7
        {
            const int nr[S] = {ir0.x, ir0.y, ir0.z, ir0.w, ir1.x, ir1.y, ir1.z, ir1.w};
            float p[S];
            #pragma unroll
            for (int s = 0; s < S; s++) p[s] = u_d * rel_feat[((unsigned)nr[s] << 6) | (unsigned)lane];

            float m1[4];
            #pragma unroll
            for (int i = 0; i < 4; i++) {
                float lo = (lane & 1) ? p[2 * i + 1] : p[2 * i];
                float hi = (lane & 1) ? p[2 * i]     : p[2 * i + 1];
                m1[i] = lo + dppx<XOR1>(hi);
            }
            float m2[2];
            #pragma unroll
            for (int i = 0; i < 2; i++) {
                float lo = (lane & 2) ? m1[2 * i + 1] : m1[2 * i];
                float hi = (lane & 2) ? m1[2 * i]     : m1[2 * i + 1];
                m2[i] = lo + dppx<XOR2>(hi);
            }
            float lo = (lane & 4) ? m2[1] : m2[0];
            float hi = (lane & 4) ? m2[0] : m2[1];
            float att = lo + __shfl_xor(hi, 4);
            att += __shfl_xor(att, 8);
            att += __shfl_xor(att, 16);
            att += __shfl_xor(att, 32);
            octet_softmax(att, w);
        }
        float agg_ii = 0.f;
        {
            const int ni[S] = {ii0.x, ii0.y, ii0.z, ii0.w, ii1.x, ii1.y, ii1.z, ii1.w};
            float r[S];
            #pragma unroll
            for (int s = 0; s < S; s++) r[s] = item_feat[((unsigned)ni[s] << 6) | (unsigned)lane];
            #pragma unroll
            for (int s = 0; s < S; s++) agg_ii = fmaf(w[s], r[s], agg_ii);
        }

        // item_h = relu(x @ Wv + bv)
        float hv;
        {
            __threadfence_block();
            xw[lane] = v_d + agg_iu + agg_ii;
            __threadfence_block();
            float a0 = 0.f, a1 = 0.f, a2 = 0.f, a3 = 0.f;
            #pragma unroll
            for (int k = 0; k < DIM / 4; k++) {
                float4 xv = xw4[k];
                float4 wv = wvT[k];
                a0 = fmaf(xv.x, wv.x, a0);
                a1 = fmaf(xv.y, wv.y, a1);
                a2 = fmaf(xv.z, wv.z, a2);
                a3 = fmaf(xv.w, wv.w, a3);
            }
            hv = fmaxf((a0 + a1) + (a2 + a3) + bv_l, 0.f);
        }

        // score = sigmoid(dot(user_h, item_h)) * 5
        float p = hu * hv;
        p += dppx<XOR1>(p);
        p += dppx<XOR2>(p);
        p += __shfl_xor(p, 4);
        p += __shfl_xor(p, 8);
        p += __shfl_xor(p, 16);
        p += __shfl_xor(p, 32);
        if (lane == 0) out[b] = 5.0f / (1.0f + __expf(-p));

        b = b2;
        u = u_nxt;
        v = v_nxt;
    }
}

extern "C" void kernel_launch(void* const* d_in, const int* in_sizes, int n_in,
                              void* d_out, int out_size, void* d_ws, size_t ws_size,
                              hipStream_t stream) {
    const int*   u_idx        = (const int*)  d_in[0];
    const int*   v_idx        = (const int*)  d_in[1];
    const float* usr_feat     = (const float*)d_in[2];
    const float* item_feat    = (const float*)d_in[3];
    const float* rel_feat     = (const float*)d_in[4];
    const int*   neigh_uu     = (const int*)  d_in[5];
    const float* neigh_uu_st  = (const float*)d_in[6];
    const int*   neigh_ui     = (const int*)  d_in[7];
    const float* neigh_ui_rat = (const float*)d_in[8];
    const float* neigh_ui_vot = (const float*)d_in[9];
    const float* neigh_ui_tim = (const float*)d_in[10];
    const int*   neigh_iu     = (const int*)  d_in[11];
    const float* neigh_iu_rat = (const float*)d_in[12];
    const float* neigh_iu_vot = (const float*)d_in[13];
    const float* neigh_iu_tim = (const float*)d_in[14];
    const int*   neigh_ii     = (const int*)  d_in[15];
    const int*   neigh_ir     = (const int*)  d_in[16];
    const float* Wu           = (const float*)d_in[17];
    const float* bu           = (const float*)d_in[18];
    const float* Wv           = (const float*)d_in[19];
    const float* bv           = (const float*)d_in[20];
    float*       out          = (float*)d_out;

    const int n = in_sizes[0];
    int blocks = (n + WPB - 1) / WPB;
    if (blocks > GRID) blocks = GRID;
    sestkgcn_kernel<<<blocks, BLOCK, 0, stream>>>(
        u_idx, v_idx, usr_feat, item_feat, rel_feat,
        neigh_uu, neigh_uu_st, neigh_ui, neigh_ui_rat, neigh_ui_vot, neigh_ui_tim,
        neigh_iu, neigh_iu_rat, neigh_iu_vot, neigh_iu_tim, neigh_ii, neigh_ir,
        Wu, bu, Wv, bv, out, n);
}

// Round 7
// 257.545 us; speedup vs baseline: 1.2303x; 1.2303x over previous
//
#include <hip/hip_runtime.h>
#include <math.h>

constexpr int DIM = 64;
constexpr int S = 8;
constexpr int WPB = 8;                 // waves per block (512 threads)
constexpr int BLOCK = WPB * 64;
constexpr int GRID = 1024;             // 4 blocks/CU resident (thread cap) x 256 CU
constexpr int BSTR = 33;               // W^T packed row stride in dwords: bank=(j+k)%32 -> 2-way only (free)

// DPP quad-perm lane exchange (VALU pipe, not DS) — correctness verified R3/R4/R5
template <int CTRL>
__device__ __forceinline__ float dppx(float x) {
    return __builtin_bit_cast(float,
        __builtin_amdgcn_mov_dpp(__builtin_bit_cast(int, x), CTRL, 0xf, 0xf, true));
}
#define XOR1 0xB1   // quad_perm(1,0,3,2)
#define XOR2 0x4E   // quad_perm(2,3,0,1)

// pack two floats as bf16 (RNE-ish) into one dword: lo=a, hi=b
__device__ __forceinline__ unsigned pk_bf16(float a, float b) {
    unsigned ua = __builtin_bit_cast(unsigned, a);
    unsigned ub = __builtin_bit_cast(unsigned, b);
    ua = (ua + 0x8000u) >> 16;
    ub = (ub + 0x8000u) & 0xffff0000u;
    return ua | ub;
}

// 8-way softmax over lanes' (lane&7) scores; broadcasts w[0..7] to all lanes.
__device__ __forceinline__ void octet_softmax(float sc, float* wout) {
    float m = sc;
    m = fmaxf(m, dppx<XOR1>(m));
    m = fmaxf(m, dppx<XOR2>(m));
    m = fmaxf(m, __shfl_xor(m, 4));
    float e = __expf(sc - m);
    float s = e;
    s += dppx<XOR1>(s);
    s += dppx<XOR2>(s);
    s += __shfl_xor(s, 4);
    float w = e / s;
    #pragma unroll
    for (int k = 0; k < 8; k++) wout[k] = __shfl(w, k);   // lane k (mod 8) holds s=k
}

__global__ __launch_bounds__(BLOCK)
void sestkgcn_kernel(
    const int*   __restrict__ u_idx,
    const int*   __restrict__ v_idx,
    const float* __restrict__ usr_feat,
    const float* __restrict__ item_feat,
    const float* __restrict__ rel_feat,
    const int*   __restrict__ neigh_uu,
    const float* __restrict__ neigh_uu_st,
    const int*   __restrict__ neigh_ui,
    const float* __restrict__ neigh_ui_rat,
    const float* __restrict__ neigh_ui_vot,
    const float* __restrict__ neigh_ui_tim,
    const int*   __restrict__ neigh_iu,
    const float* __restrict__ neigh_iu_rat,
    const float* __restrict__ neigh_iu_vot,
    const float* __restrict__ neigh_iu_tim,
    const int*   __restrict__ neigh_ii,
    const int*   __restrict__ neigh_ir,
    const float* __restrict__ Wu,
    const float* __restrict__ bu,
    const float* __restrict__ Wv,
    const float* __restrict__ bv,
    float*       __restrict__ out,
    int n)
{
    // packed bf16 W^T: sWuP[j*BSTR + m] = {bf16 Wu[m][j], bf16 Wu[m+32][j]}, m=0..31
    __shared__ unsigned sWuP[DIM * BSTR];
    __shared__ unsigned sWvP[DIM * BSTR];
    __shared__ float sbu[DIM];
    __shared__ float sbv[DIM];
    __shared__ float xs[WPB * DIM];

    const int tid = threadIdx.x;
    for (int i = tid; i < DIM * 32; i += BLOCK) {
        const int j_ = i & 63, m_ = i >> 6;          // m_ = 0..31
        sWuP[j_ * BSTR + m_] = pk_bf16(Wu[m_ * DIM + j_], Wu[(m_ + 32) * DIM + j_]);
        sWvP[j_ * BSTR + m_] = pk_bf16(Wv[m_ * DIM + j_], Wv[(m_ + 32) * DIM + j_]);
    }
    if (tid < DIM) { sbu[tid] = bu[tid]; sbv[tid] = bv[tid]; }
    __syncthreads();

    const int wave = tid >> 6;
    const int lane = tid & 63;
    const int ls   = lane & 7;

    float* xw = &xs[wave * DIM];
    const unsigned* wuP = &sWuP[lane * BSTR];
    const unsigned* wvP = &sWvP[lane * BSTR];
    const float4* xw4 = (const float4*)xw;
    const float bu_l = sbu[lane];
    const float bv_l = sbv[lane];

    const int stride = GRID * WPB;
    int b = blockIdx.x * WPB + wave;
    if (b >= n) return;

    int u = u_idx[b];
    int v = v_idx[b];

    while (b < n) {
        const int b2 = b + stride;
        const int bc = (b2 < n) ? b2 : b;
        const int u_nxt = u_idx[bc];
        const int v_nxt = v_idx[bc];

        const unsigned u8 = (unsigned)u << 3, v8 = (unsigned)v << 3;

        const float u_d = usr_feat[((unsigned)u << 6) | (unsigned)lane];
        const float v_d = item_feat[((unsigned)v << 6) | (unsigned)lane];

        const float sc_uu = neigh_uu_st[u8 + ls];
        const float sc_ui = neigh_ui_rat[u8 + ls] * neigh_ui_vot[u8 + ls] * neigh_ui_tim[u8 + ls];
        const float sc_iu = neigh_iu_rat[v8 + ls] * neigh_iu_vot[v8 + ls] * neigh_iu_tim[v8 + ls];

        // ---------------- user side ----------------
        float w[S];
        octet_softmax(sc_uu, w);
        float agg_uu = 0.f;
        {
            const int4 i0 = ((const int4*)(neigh_uu + u8))[0];
            const int4 i1 = ((const int4*)(neigh_uu + u8))[1];
            const int ni[S] = {i0.x, i0.y, i0.z, i0.w, i1.x, i1.y, i1.z, i1.w};
            float r[S];
            #pragma unroll
            for (int s = 0; s < S; s++) r[s] = usr_feat[((unsigned)ni[s] << 6) | (unsigned)lane];
            #pragma unroll
            for (int s = 0; s < S; s++) agg_uu = fmaf(w[s], r[s], agg_uu);
        }

        octet_softmax(sc_ui, w);
        float agg_ui = 0.f;
        {
            const int4 i0 = ((const int4*)(neigh_ui + u8))[0];
            const int4 i1 = ((const int4*)(neigh_ui + u8))[1];
            const int ni[S] = {i0.x, i0.y, i0.z, i0.w, i1.x, i1.y, i1.z, i1.w};
            float r[S];
            #pragma unroll
            for (int s = 0; s < S; s++) r[s] = item_feat[((unsigned)ni[s] << 6) | (unsigned)lane];
            #pragma unroll
            for (int s = 0; s < S; s++) agg_ui = fmaf(w[s], r[s], agg_ui);
        }

        // user_h = relu(x @ Wu + bu); bf16-packed W, dims m and m+32 per dword
        float hu;
        {
            xw[lane] = u_d + agg_uu + agg_ui;
            __threadfence_block();
            float a0 = 0.f, a1 = 0.f;
            #pragma unroll
            for (int k = 0; k < 8; k++) {
                const float4 xa = xw4[k];        // dims 4k..4k+3
                const float4 xb = xw4[k + 8];    // dims 32+4k..32+4k+3
                #pragma unroll
                for (int t = 0; t < 4; t++) {
                    const unsigned wd = wuP[4 * k + t];
                    const float wlo = __builtin_bit_cast(float, wd << 16);
                    const float whi = __builtin_bit_cast(float, wd & 0xffff0000u);
                    const float xat = (t == 0) ? xa.x : (t == 1) ? xa.y : (t == 2) ? xa.z : xa.w;
                    const float xbt = (t == 0) ? xb.x : (t == 1) ? xb.y : (t == 2) ? xb.z : xb.w;
                    a0 = fmaf(xat, wlo, a0);
                    a1 = fmaf(xbt, whi, a1);
                }
            }
            hu = fmaxf(a0 + a1 + bu_l, 0.f);
        }

        // ---------------- item side ----------------
        octet_softmax(sc_iu, w);
        float agg_iu = 0.f;
        {
            const int4 i0 = ((const int4*)(neigh_iu + v8))[0];
            const int4 i1 = ((const int4*)(neigh_iu + v8))[1];
            const int ni[S] = {i0.x, i0.y, i0.z, i0.w, i1.x, i1.y, i1.z, i1.w};
            float r[S];
            #pragma unroll
            for (int s = 0; s < S; s++) r[s] = usr_feat[((unsigned)ni[s] << 6) | (unsigned)lane];
            #pragma unroll
            for (int s = 0; s < S; s++) agg_iu = fmaf(w[s], r[s], agg_iu);
        }

        // KG attention: merge 8 dot-products so lane holds total for s=lane&7
        {
            const int4 r0 = ((const int4*)(neigh_ir + v8))[0];
            const int4 r1 = ((const int4*)(neigh_ir + v8))[1];
            const int nr[S] = {r0.x, r0.y, r0.z, r0.w, r1.x, r1.y, r1.z, r1.w};
            float p[S];
            #pragma unroll
            for (int s = 0; s < S; s++) p[s] = u_d * rel_feat[((unsigned)nr[s] << 6) | (unsigned)lane];

            float m1[4];
            #pragma unroll
            for (int i = 0; i < 4; i++) {
                float lo = (lane & 1) ? p[2 * i + 1] : p[2 * i];
                float hi = (lane & 1) ? p[2 * i]     : p[2 * i + 1];
                m1[i] = lo + dppx<XOR1>(hi);
            }
            float m2[2];
            #pragma unroll
            for (int i = 0; i < 2; i++) {
                float lo = (lane & 2) ? m1[2 * i + 1] : m1[2 * i];
                float hi = (lane & 2) ? m1[2 * i]     : m1[2 * i + 1];
                m2[i] = lo + dppx<XOR2>(hi);
            }
            float lo = (lane & 4) ? m2[1] : m2[0];
            float hi = (lane & 4) ? m2[0] : m2[1];
            float att = lo + __shfl_xor(hi, 4);
            att += __shfl_xor(att, 8);
            att += __shfl_xor(att, 16);
            att += __shfl_xor(att, 32);
            octet_softmax(att, w);
        }
        float agg_ii = 0.f;
        {
            const int4 i0 = ((const int4*)(neigh_ii + v8))[0];
            const int4 i1 = ((const int4*)(neigh_ii + v8))[1];
            const int ni[S] = {i0.x, i0.y, i0.z, i0.w, i1.x, i1.y, i1.z, i1.w};
            float r[S];
            #pragma unroll
            for (int s = 0; s < S; s++) r[s] = item_feat[((unsigned)ni[s] << 6) | (unsigned)lane];
            #pragma unroll
            for (int s = 0; s < S; s++) agg_ii = fmaf(w[s], r[s], agg_ii);
        }

        // item_h = relu(x @ Wv + bv)
        float hv;
        {
            __threadfence_block();
            xw[lane] = v_d + agg_iu + agg_ii;
            __threadfence_block();
            float a0 = 0.f, a1 = 0.f;
            #pragma unroll
            for (int k = 0; k < 8; k++) {
                const float4 xa = xw4[k];
                const float4 xb = xw4[k + 8];
                #pragma unroll
                for (int t = 0; t < 4; t++) {
                    const unsigned wd = wvP[4 * k + t];
                    const float wlo = __builtin_bit_cast(float, wd << 16);
                    const float whi = __builtin_bit_cast(float, wd & 0xffff0000u);
                    const float xat = (t == 0) ? xa.x : (t == 1) ? xa.y : (t == 2) ? xa.z : xa.w;
                    const float xbt = (t == 0) ? xb.x : (t == 1) ? xb.y : (t == 2) ? xb.z : xb.w;
                    a0 = fmaf(xat, wlo, a0);
                    a1 = fmaf(xbt, whi, a1);
                }
            }
            hv = fmaxf(a0 + a1 + bv_l, 0.f);
        }

        // score = sigmoid(dot(user_h, item_h)) * 5
        float p = hu * hv;
        p += dppx<XOR1>(p);
        p += dppx<XOR2>(p);
        p += __shfl_xor(p, 4);
        p += __shfl_xor(p, 8);
        p += __shfl_xor(p, 16);
        p += __shfl_xor(p, 32);
        if (lane == 0) out[b] = 5.0f / (1.0f + __expf(-p));

        b = b2;
        u = u_nxt;
        v = v_nxt;
    }
}

extern "C" void kernel_launch(void* const* d_in, const int* in_sizes, int n_in,
                              void* d_out, int out_size, void* d_ws, size_t ws_size,
                              hipStream_t stream) {
    const int*   u_idx        = (const int*)  d_in[0];
    const int*   v_idx        = (const int*)  d_in[1];
    const float* usr_feat     = (const float*)d_in[2];
    const float* item_feat    = (const float*)d_in[3];
    const float* rel_feat     = (const float*)d_in[4];
    const int*   neigh_uu     = (const int*)  d_in[5];
    const float* neigh_uu_st  = (const float*)d_in[6];
    const int*   neigh_ui     = (const int*)  d_in[7];
    const float* neigh_ui_rat = (const float*)d_in[8];
    const float* neigh_ui_vot = (const float*)d_in[9];
    const float* neigh_ui_tim = (const float*)d_in[10];
    const int*   neigh_iu     = (const int*)  d_in[11];
    const float* neigh_iu_rat = (const float*)d_in[12];
    const float* neigh_iu_vot = (const float*)d_in[13];
    const float* neigh_iu_tim = (const float*)d_in[14];
    const int*   neigh_ii     = (const int*)  d_in[15];
    const int*   neigh_ir     = (const int*)  d_in[16];
    const float* Wu           = (const float*)d_in[17];
    const float* bu           = (const float*)d_in[18];
    const float* Wv           = (const float*)d_in[19];
    const float* bv           = (const float*)d_in[20];
    float*       out          = (float*)d_out;

    const int n = in_sizes[0];
    int blocks = (n + WPB - 1) / WPB;
    if (blocks > GRID) blocks = GRID;
    sestkgcn_kernel<<<blocks, BLOCK, 0, stream>>>(
        u_idx, v_idx, usr_feat, item_feat, rel_feat,
        neigh_uu, neigh_uu_st, neigh_ui, neigh_ui_rat, neigh_ui_vot, neigh_ui_tim,
        neigh_iu, neigh_iu_rat, neigh_iu_vot, neigh_iu_tim, neigh_ii, neigh_ir,
        Wu, bu, Wv, bv, out, n);
}

// Round 8
// 247.819 us; speedup vs baseline: 1.2785x; 1.0392x over previous
//
#include <hip/hip_runtime.h>
#include <math.h>

constexpr int DIM = 64;
constexpr int S = 8;
constexpr int WPB = 16;                // waves per block (1024 threads) — R5 showed 82% occ w/ 1024-thr blocks
constexpr int BLOCK = WPB * 64;
constexpr int GRID = 512;              // 2 blocks/CU x 256 CU; grid-stride over batch
constexpr int BSTR = 33;               // packed W^T row stride in dwords: bank=(j+k)%32 -> 2-way only (free)

// DPP quad-perm lane exchange (VALU pipe, not DS) — correctness verified R3-R6
template <int CTRL>
__device__ __forceinline__ float dppx(float x) {
    return __builtin_bit_cast(float,
        __builtin_amdgcn_mov_dpp(__builtin_bit_cast(int, x), CTRL, 0xf, 0xf, true));
}
#define XOR1 0xB1   // quad_perm(1,0,3,2)
#define XOR2 0x4E   // quad_perm(2,3,0,1)

// pack two floats as bf16 (RNE-ish) into one dword: lo=a, hi=b  (absmax 0.031 verified R6)
__device__ __forceinline__ unsigned pk_bf16(float a, float b) {
    unsigned ua = __builtin_bit_cast(unsigned, a);
    unsigned ub = __builtin_bit_cast(unsigned, b);
    ua = (ua + 0x8000u) >> 16;
    ub = (ub + 0x8000u) & 0xffff0000u;
    return ua | ub;
}

// 8-way softmax over lanes' (lane&7) scores; broadcasts w[0..7] to all lanes.
__device__ __forceinline__ void octet_softmax(float sc, float* wout) {
    float m = sc;
    m = fmaxf(m, dppx<XOR1>(m));
    m = fmaxf(m, dppx<XOR2>(m));
    m = fmaxf(m, __shfl_xor(m, 4));
    float e = __expf(sc - m);
    float s = e;
    s += dppx<XOR1>(s);
    s += dppx<XOR2>(s);
    s += __shfl_xor(s, 4);
    float w = e / s;
    #pragma unroll
    for (int k = 0; k < 8; k++) wout[k] = __shfl(w, k);   // lane k (mod 8) holds s=k
}

__global__ __launch_bounds__(BLOCK)
void sestkgcn_kernel(
    const int*   __restrict__ u_idx,
    const int*   __restrict__ v_idx,
    const float* __restrict__ usr_feat,
    const float* __restrict__ item_feat,
    const float* __restrict__ rel_feat,
    const int*   __restrict__ neigh_uu,
    const float* __restrict__ neigh_uu_st,
    const int*   __restrict__ neigh_ui,
    const float* __restrict__ neigh_ui_rat,
    const float* __restrict__ neigh_ui_vot,
    const float* __restrict__ neigh_ui_tim,
    const int*   __restrict__ neigh_iu,
    const float* __restrict__ neigh_iu_rat,
    const float* __restrict__ neigh_iu_vot,
    const float* __restrict__ neigh_iu_tim,
    const int*   __restrict__ neigh_ii,
    const int*   __restrict__ neigh_ir,
    const float* __restrict__ Wu,
    const float* __restrict__ bu,
    const float* __restrict__ Wv,
    const float* __restrict__ bv,
    float*       __restrict__ out,
    int n)
{
    // packed bf16 W^T: sWuP[j*BSTR + m] = {bf16 Wu[m][j], bf16 Wu[m+32][j]}, m=0..31
    __shared__ unsigned sWuP[DIM * BSTR];
    __shared__ unsigned sWvP[DIM * BSTR];
    __shared__ float sbu[DIM];
    __shared__ float sbv[DIM];
    __shared__ float xs[WPB * DIM];

    const int tid = threadIdx.x;
    for (int i = tid; i < DIM * 32; i += BLOCK) {
        const int j_ = i & 63, m_ = i >> 6;          // m_ = 0..31
        sWuP[j_ * BSTR + m_] = pk_bf16(Wu[m_ * DIM + j_], Wu[(m_ + 32) * DIM + j_]);
        sWvP[j_ * BSTR + m_] = pk_bf16(Wv[m_ * DIM + j_], Wv[(m_ + 32) * DIM + j_]);
    }
    if (tid < DIM) { sbu[tid] = bu[tid]; sbv[tid] = bv[tid]; }
    __syncthreads();

    const int wave = tid >> 6;
    const int lane = tid & 63;
    const int ls   = lane & 7;

    float* xw = &xs[wave * DIM];
    const unsigned* wuP = &sWuP[lane * BSTR];
    const unsigned* wvP = &sWvP[lane * BSTR];
    const float4* xw4 = (const float4*)xw;
    const float bu_l = sbu[lane];
    const float bv_l = sbv[lane];

    const int stride = GRID * WPB;
    int b = blockIdx.x * WPB + wave;
    if (b >= n) return;

    int u = u_idx[b];
    int v = v_idx[b];

    while (b < n) {
        const int b2 = b + stride;
        const int bc = (b2 < n) ? b2 : b;
        const int u_nxt = u_idx[bc];
        const int v_nxt = v_idx[bc];

        const unsigned u8 = (unsigned)u << 3, v8 = (unsigned)v << 3;

        const float u_d = usr_feat[((unsigned)u << 6) | (unsigned)lane];
        const float v_d = item_feat[((unsigned)v << 6) | (unsigned)lane];

        const float sc_uu = neigh_uu_st[u8 + ls];
        const float sc_ui = neigh_ui_rat[u8 + ls] * neigh_ui_vot[u8 + ls] * neigh_ui_tim[u8 + ls];
        const float sc_iu = neigh_iu_rat[v8 + ls] * neigh_iu_vot[v8 + ls] * neigh_iu_tim[v8 + ls];

        // ---------------- user side ----------------
        float w[S];
        octet_softmax(sc_uu, w);
        float agg_uu = 0.f;
        {
            const int4 i0 = ((const int4*)(neigh_uu + u8))[0];
            const int4 i1 = ((const int4*)(neigh_uu + u8))[1];
            const int ni[S] = {i0.x, i0.y, i0.z, i0.w, i1.x, i1.y, i1.z, i1.w};
            float r[S];
            #pragma unroll
            for (int s = 0; s < S; s++) r[s] = usr_feat[((unsigned)ni[s] << 6) | (unsigned)lane];
            #pragma unroll
            for (int s = 0; s < S; s++) agg_uu = fmaf(w[s], r[s], agg_uu);
        }

        octet_softmax(sc_ui, w);
        float agg_ui = 0.f;
        {
            const int4 i0 = ((const int4*)(neigh_ui + u8))[0];
            const int4 i1 = ((const int4*)(neigh_ui + u8))[1];
            const int ni[S] = {i0.x, i0.y, i0.z, i0.w, i1.x, i1.y, i1.z, i1.w};
            float r[S];
            #pragma unroll
            for (int s = 0; s < S; s++) r[s] = item_feat[((unsigned)ni[s] << 6) | (unsigned)lane];
            #pragma unroll
            for (int s = 0; s < S; s++) agg_ui = fmaf(w[s], r[s], agg_ui);
        }

        // user_h = relu(x @ Wu + bu); bf16-packed W, dims m and m+32 per dword
        float hu;
        {
            xw[lane] = u_d + agg_uu + agg_ui;
            __threadfence_block();
            float a0 = 0.f, a1 = 0.f;
            #pragma unroll
            for (int k = 0; k < 8; k++) {
                const float4 xa = xw4[k];        // dims 4k..4k+3
                const float4 xb = xw4[k + 8];    // dims 32+4k..32+4k+3
                #pragma unroll
                for (int t = 0; t < 4; t++) {
                    const unsigned wd = wuP[4 * k + t];
                    const float wlo = __builtin_bit_cast(float, wd << 16);
                    const float whi = __builtin_bit_cast(float, wd & 0xffff0000u);
                    const float xat = (t == 0) ? xa.x : (t == 1) ? xa.y : (t == 2) ? xa.z : xa.w;
                    const float xbt = (t == 0) ? xb.x : (t == 1) ? xb.y : (t == 2) ? xb.z : xb.w;
                    a0 = fmaf(xat, wlo, a0);
                    a1 = fmaf(xbt, whi, a1);
                }
            }
            hu = fmaxf(a0 + a1 + bu_l, 0.f);
        }

        // ---------------- item side ----------------
        octet_softmax(sc_iu, w);
        float agg_iu = 0.f;
        {
            const int4 i0 = ((const int4*)(neigh_iu + v8))[0];
            const int4 i1 = ((const int4*)(neigh_iu + v8))[1];
            const int ni[S] = {i0.x, i0.y, i0.z, i0.w, i1.x, i1.y, i1.z, i1.w};
            float r[S];
            #pragma unroll
            for (int s = 0; s < S; s++) r[s] = usr_feat[((unsigned)ni[s] << 6) | (unsigned)lane];
            #pragma unroll
            for (int s = 0; s < S; s++) agg_iu = fmaf(w[s], r[s], agg_iu);
        }

        // KG attention: merge 8 dot-products so lane holds total for s=lane&7
        {
            const int4 r0 = ((const int4*)(neigh_ir + v8))[0];
            const int4 r1 = ((const int4*)(neigh_ir + v8))[1];
            const int nr[S] = {r0.x, r0.y, r0.z, r0.w, r1.x, r1.y, r1.z, r1.w};
            float p[S];
            #pragma unroll
            for (int s = 0; s < S; s++) p[s] = u_d * rel_feat[((unsigned)nr[s] << 6) | (unsigned)lane];

            float m1[4];
            #pragma unroll
            for (int i = 0; i < 4; i++) {
                float lo = (lane & 1) ? p[2 * i + 1] : p[2 * i];
                float hi = (lane & 1) ? p[2 * i]     : p[2 * i + 1];
                m1[i] = lo + dppx<XOR1>(hi);
            }
            float m2[2];
            #pragma unroll
            for (int i = 0; i < 2; i++) {
                float lo = (lane & 2) ? m1[2 * i + 1] : m1[2 * i];
                float hi = (lane & 2) ? m1[2 * i]     : m1[2 * i + 1];
                m2[i] = lo + dppx<XOR2>(hi);
            }
            float lo = (lane & 4) ? m2[1] : m2[0];
            float hi = (lane & 4) ? m2[0] : m2[1];
            float att = lo + __shfl_xor(hi, 4);
            att += __shfl_xor(att, 8);
            att += __shfl_xor(att, 16);
            att += __shfl_xor(att, 32);
            octet_softmax(att, w);
        }
        float agg_ii = 0.f;
        {
            const int4 i0 = ((const int4*)(neigh_ii + v8))[0];
            const int4 i1 = ((const int4*)(neigh_ii + v8))[1];
            const int ni[S] = {i0.x, i0.y, i0.z, i0.w, i1.x, i1.y, i1.z, i1.w};
            float r[S];
            #pragma unroll
            for (int s = 0; s < S; s++) r[s] = item_feat[((unsigned)ni[s] << 6) | (unsigned)lane];
            #pragma unroll
            for (int s = 0; s < S; s++) agg_ii = fmaf(w[s], r[s], agg_ii);
        }

        // item_h = relu(x @ Wv + bv)
        float hv;
        {
            __threadfence_block();
            xw[lane] = v_d + agg_iu + agg_ii;
            __threadfence_block();
            float a0 = 0.f, a1 = 0.f;
            #pragma unroll
            for (int k = 0; k < 8; k++) {
                const float4 xa = xw4[k];
                const float4 xb = xw4[k + 8];
                #pragma unroll
                for (int t = 0; t < 4; t++) {
                    const unsigned wd = wvP[4 * k + t];
                    const float wlo = __builtin_bit_cast(float, wd << 16);
                    const float whi = __builtin_bit_cast(float, wd & 0xffff0000u);
                    const float xat = (t == 0) ? xa.x : (t == 1) ? xa.y : (t == 2) ? xa.z : xa.w;
                    const float xbt = (t == 0) ? xb.x : (t == 1) ? xb.y : (t == 2) ? xb.z : xb.w;
                    a0 = fmaf(xat, wlo, a0);
                    a1 = fmaf(xbt, whi, a1);
                }
            }
            hv = fmaxf(a0 + a1 + bv_l, 0.f);
        }

        // score = sigmoid(dot(user_h, item_h)) * 5
        float p = hu * hv;
        p += dppx<XOR1>(p);
        p += dppx<XOR2>(p);
        p += __shfl_xor(p, 4);
        p += __shfl_xor(p, 8);
        p += __shfl_xor(p, 16);
        p += __shfl_xor(p, 32);
        if (lane == 0) out[b] = 5.0f / (1.0f + __expf(-p));

        b = b2;
        u = u_nxt;
        v = v_nxt;
    }
}

extern "C" void kernel_launch(void* const* d_in, const int* in_sizes, int n_in,
                              void* d_out, int out_size, void* d_ws, size_t ws_size,
                              hipStream_t stream) {
    const int*   u_idx        = (const int*)  d_in[0];
    const int*   v_idx        = (const int*)  d_in[1];
    const float* usr_feat     = (const float*)d_in[2];
    const float* item_feat    = (const float*)d_in[3];
    const float* rel_feat     = (const float*)d_in[4];
    const int*   neigh_uu     = (const int*)  d_in[5];
    const float* neigh_uu_st  = (const float*)d_in[6];
    const int*   neigh_ui     = (const int*)  d_in[7];
    const float* neigh_ui_rat = (const float*)d_in[8];
    const float* neigh_ui_vot = (const float*)d_in[9];
    const float* neigh_ui_tim = (const float*)d_in[10];
    const int*   neigh_iu     = (const int*)  d_in[11];
    const float* neigh_iu_rat = (const float*)d_in[12];
    const float* neigh_iu_vot = (const float*)d_in[13];
    const float* neigh_iu_tim = (const float*)d_in[14];
    const int*   neigh_ii     = (const int*)  d_in[15];
    const int*   neigh_ir     = (const int*)  d_in[16];
    const float* Wu           = (const float*)d_in[17];
    const float* bu           = (const float*)d_in[18];
    const float* Wv           = (const float*)d_in[19];
    const float* bv           = (const float*)d_in[20];
    float*       out          = (float*)d_out;

    const int n = in_sizes[0];
    int blocks = (n + WPB - 1) / WPB;
    if (blocks > GRID) blocks = GRID;
    sestkgcn_kernel<<<blocks, BLOCK, 0, stream>>>(
        u_idx, v_idx, usr_feat, item_feat, rel_feat,
        neigh_uu, neigh_uu_st, neigh_ui, neigh_ui_rat, neigh_ui_vot, neigh_ui_tim,
        neigh_iu, neigh_iu_rat, neigh_iu_vot, neigh_iu_tim, neigh_ii, neigh_ir,
        Wu, bu, Wv, bv, out, n);
}